// Round 7
// baseline (465.077 us; speedup 1.0000x reference)
//
#include <hip/hip_runtime.h>
#include <hip/hip_bf16.h>

#define D      128
#define LG     8
#define CHUNK  256   // (1 << LG)

typedef __attribute__((ext_vector_type(8))) short          short8;
typedef __attribute__((ext_vector_type(8))) unsigned short ushort8;
typedef __attribute__((ext_vector_type(4))) float          floatx4;
typedef __attribute__((ext_vector_type(2))) float          floatx2;
typedef __attribute__((ext_vector_type(2))) unsigned       uintx2;

__device__ inline float b2f(unsigned short u) {
    return __uint_as_float(((unsigned)u) << 16);
}
__device__ inline unsigned short f2bf(float f) {
    __hip_bfloat16 h = __float2bfloat16(f);
    unsigned short u;
    __builtin_memcpy(&u, &h, 2);
    return u;
}

__device__ inline void atomicMaxF(float* addr, float v) {
    if (v >= 0.f) atomicMax((int*)addr, __float_as_int(v));
    else          atomicMin((unsigned int*)addr, __float_as_uint(v));
}

__global__ void init_out_kernel(float* out, int out_size) {
    int t = threadIdx.x;
    if (t < out_size) out[t] = -INFINITY;
}

// K1: block = one 256-node chunk. Encode y = W*emb[tok] via MFMA (W in regs,
// wave-pair split over the 128 output dims), chunk-local inclusive cumsum T in
// LDS (fp32 accum, bf16 store, XOR-swizzled granules), finish h + max for all
// non-crossing nodes, export T rows (linear bf16) + chunk total.
__global__ __launch_bounds__(256, 2) void fused_kernel(
        const int* __restrict__ tokens, const int* __restrict__ ends,
        const float* __restrict__ emb, const float* __restrict__ W,
        const float* __restrict__ bvec, unsigned short* __restrict__ T_sp,
        float* __restrict__ sumE, float* __restrict__ out, int n) {
    __shared__ ushort8 Tl[CHUNK * 16];   // 64 KB: row r, granule g at (r<<4)|(g^(r&7))
    __shared__ int s_tok[CHUNK];
    __shared__ int s_end[CHUNK];
    __shared__ floatx2 redf[4][64];
    int tid = threadIdx.x, cb = blockIdx.x;
    int i0 = cb << LG, cnt = min(CHUNK, n - i0);
    {
        int gi = i0 + tid;
        s_tok[tid] = tokens[min(gi, n - 1)];
        s_end[tid] = (gi < n) ? ends[gi] : gi;
    }
    __syncthreads();

    int lane = tid & 63, wid = tid >> 6;
    int c = lane & 15, kg = lane >> 4;
    int tw = wid & 1, pair = wid >> 1;

    // A = W fragments: out-tile to = tw*4+tl; A row = to*16+c, k = kk*32+kg*8.
    short8 Wf[4][4];
    #pragma unroll
    for (int tl = 0; tl < 4; ++tl) {
        const float* wr = W + (size_t)((tw * 4 + tl) * 16 + c) * D + kg * 8;
        #pragma unroll
        for (int kk = 0; kk < 4; ++kk) {
            floatx4 f0 = *(const floatx4*)(wr + kk * 32);
            floatx4 f1 = *(const floatx4*)(wr + kk * 32 + 4);
            short8 w;
            #pragma unroll
            for (int j = 0; j < 4; ++j) { w[j] = (short)f2bf(f0[j]); w[j + 4] = (short)f2bf(f1[j]); }
            Wf[tl][kk] = w;
        }
    }

    // Encode phase: pair handles node tiles [pair*8, pair*8+8).
    int tiles = (cnt + 15) >> 4;
    int Tend = min(pair * 8 + 8, tiles);
    for (int T_ = pair * 8; T_ < Tend; ++T_) {
        int r = T_ * 16 + c;             // node this lane gathers (B column)
        const float* er = emb + (size_t)s_tok[r] * D + kg * 8;
        short8 Bf[4];
        #pragma unroll
        for (int kk = 0; kk < 4; ++kk) {
            floatx4 f0 = *(const floatx4*)(er + kk * 32);
            floatx4 f1 = *(const floatx4*)(er + kk * 32 + 4);
            short8 bfr;
            #pragma unroll
            for (int j = 0; j < 4; ++j) { bfr[j] = (short)f2bf(f0[j]); bfr[j + 4] = (short)f2bf(f1[j]); }
            Bf[kk] = bfr;
        }
        #pragma unroll
        for (int tl = 0; tl < 4; ++tl) {
            floatx4 acc = {0.f, 0.f, 0.f, 0.f};
            acc = __builtin_amdgcn_mfma_f32_16x16x32_bf16(Wf[tl][0], Bf[0], acc, 0, 0, 0);
            acc = __builtin_amdgcn_mfma_f32_16x16x32_bf16(Wf[tl][1], Bf[1], acc, 0, 0, 0);
            acc = __builtin_amdgcn_mfma_f32_16x16x32_bf16(Wf[tl][2], Bf[2], acc, 0, 0, 0);
            acc = __builtin_amdgcn_mfma_f32_16x16x32_bf16(Wf[tl][3], Bf[3], acc, 0, 0, 0);
            // lane holds y[out = (tw*4+tl)*16 + kg*4 + i][node r] -> 4 consecutive dims
            int to = tw * 4 + tl;
            int gs = (to * 2 + (kg >> 1)) ^ (r & 7);
            unsigned u0 = ((unsigned)f2bf(acc[0])) | (((unsigned)f2bf(acc[1])) << 16);
            unsigned u1 = ((unsigned)f2bf(acc[2])) | (((unsigned)f2bf(acc[3])) << 16);
            uintx2 uu = {u0, u1};
            *(uintx2*)((char*)Tl + r * 256 + gs * 16 + (kg & 1) * 8) = uu;
        }
    }
    __syncthreads();

    // Scan phase: thread d serially accumulates over nodes (fp32), bf16 store.
    if (tid < 128) {
        int d = tid, gr = d >> 3, o = d & 7;
        unsigned short* Tb = (unsigned short*)Tl;
        float acc = 0.f;
        for (int j = 0; j < cnt; ++j) {
            int idx = j * 128 + (((gr ^ (j & 7))) << 3) + o;
            acc += b2f(Tb[idx]);
            Tb[idx] = f2bf(acc);
        }
        sumE[(size_t)cb * D + d] = acc;
    }
    __syncthreads();

    // Export T rows to global (linear layout, coalesced 16B units).
    {
        int units = cnt * 16;
        ushort8* go = (ushort8*)(T_sp + (size_t)i0 * D);
        for (int u = tid; u < units; u += 256) {
            int r = u >> 4, q = u & 15;
            go[u] = Tl[(r << 4) | (q ^ (r & 7))];
        }
    }

    // Local-h phase: wave handles nodes [wid*64, wid*64+64); one node per round
    // (wave-uniform rows); lane covers dims lane*2, lane*2+1.
    floatx2 bl = *(const floatx2*)(bvec + lane * 2);
    floatx2 hm = {-INFINITY, -INFINITY};
    for (int rr = 0; rr < 64; ++rr) {
        int j = wid * 64 + rr;
        if (j >= cnt) break;
        int e = s_end[j];
        int eloc = e - i0;
        if (eloc >= CHUNK) continue;     // crosser -> cross_kernel
        int gre = (lane >> 2) ^ (eloc & 7);
        unsigned se = *(const unsigned*)((const char*)Tl + eloc * 256 + (gre << 4) + (lane & 3) * 4);
        unsigned sp = 0u;
        if (j > 0) {
            int grp = (lane >> 2) ^ ((j - 1) & 7);
            sp = *(const unsigned*)((const char*)Tl + (j - 1) * 256 + (grp << 4) + (lane & 3) * 4);
        }
        float cf = (float)(e - (i0 + j) + 1);
        float h0 = b2f((unsigned short)(se & 0xffff)) - b2f((unsigned short)(sp & 0xffff)) + cf * bl[0];
        float h1 = b2f((unsigned short)(se >> 16))    - b2f((unsigned short)(sp >> 16))    + cf * bl[1];
        hm[0] = fmaxf(hm[0], h0);
        hm[1] = fmaxf(hm[1], h1);
    }
    redf[wid][lane] = hm;
    __syncthreads();
    if (tid < 64) {
        floatx2 a = redf[0][tid], b = redf[1][tid], cc = redf[2][tid], dd = redf[3][tid];
        float v0 = fmaxf(fmaxf(a[0], b[0]), fmaxf(cc[0], dd[0]));
        float v1 = fmaxf(fmaxf(a[1], b[1]), fmaxf(cc[1], dd[1]));
        atomicMaxF(&out[tid * 2],     v0);
        atomicMaxF(&out[tid * 2 + 1], v1);
    }
}

// K_scan: in-place exclusive scan of chunk totals (one wave per dim).
__global__ void scan_kernel(float* sumE, int C) {
    int d    = blockIdx.x;     // 0..127
    int lane = threadIdx.x;    // 0..63
    float carry = 0.f;
    for (int c0 = 0; c0 < C; c0 += 64) {
        int c = c0 + lane;
        float v = (c < C) ? sumE[(size_t)c * D + d] : 0.f;
        float incl = v;
        #pragma unroll
        for (int off = 1; off < 64; off <<= 1) {
            float t = __shfl_up(incl, off);
            if (lane >= off) incl += t;
        }
        if (c < C) sumE[(size_t)c * D + d] = carry + incl - v;  // exclusive
        carry += __shfl(incl, 63);
    }
}

// K2: crossing nodes only. Ballot-compact per 64-node window; each crosser is
// processed wave-uniformly: gather T_sp[e], T_sp[i-1] rows (bf16, coalesced
// 4B/lane) + fp32 chunk prefixes; h = (Te+pe) - (Tp+pc) + cnt*b; max-reduce.
__global__ __launch_bounds__(256, 4) void cross_kernel(
        const int* __restrict__ ends, const unsigned short* __restrict__ T_sp,
        const float* __restrict__ pref, const float* __restrict__ bvec,
        float* __restrict__ out, int n) {
    __shared__ floatx2 redf[4][64];
    int tid = threadIdx.x, lane = tid & 63, wid = tid >> 6;
    floatx2 bl = *(const floatx2*)(bvec + lane * 2);
    floatx2 hm = {-INFINITY, -INFINITY};
    int nw = (n + 63) >> 6;
    int gw = blockIdx.x * 4 + wid, stride = gridDim.x * 4;
    for (int w = gw; w < nw; w += stride) {
        int i = w * 64 + lane;
        int e = (i < n) ? ends[i] : 0;
        bool cross = (i < n) && ((e >> LG) != (i >> LG));
        unsigned long long mask = __ballot(cross);
        while (mask) {
            int b = __builtin_ctzll(mask);
            mask &= mask - 1;
            int ii = w * 64 + b;
            int ee = __shfl(e, b);
            int ci = ii >> LG, ce = ee >> LG;
            unsigned se = *(const unsigned*)(T_sp + (size_t)ee * D + lane * 2);
            unsigned sp = 0u;
            if (ii & (CHUNK - 1))
                sp = *(const unsigned*)(T_sp + (size_t)(ii - 1) * D + lane * 2);
            floatx2 pe = *(const floatx2*)(pref + (size_t)ce * D + lane * 2);
            floatx2 pc = *(const floatx2*)(pref + (size_t)ci * D + lane * 2);
            float cf = (float)(ee - ii + 1);
            float h0 = (b2f((unsigned short)(se & 0xffff)) + pe[0])
                     - (b2f((unsigned short)(sp & 0xffff)) + pc[0]) + cf * bl[0];
            float h1 = (b2f((unsigned short)(se >> 16)) + pe[1])
                     - (b2f((unsigned short)(sp >> 16)) + pc[1]) + cf * bl[1];
            hm[0] = fmaxf(hm[0], h0);
            hm[1] = fmaxf(hm[1], h1);
        }
    }
    redf[wid][lane] = hm;
    __syncthreads();
    if (tid < 64) {
        floatx2 a = redf[0][tid], b = redf[1][tid], cc = redf[2][tid], dd = redf[3][tid];
        float v0 = fmaxf(fmaxf(a[0], b[0]), fmaxf(cc[0], dd[0]));
        float v1 = fmaxf(fmaxf(a[1], b[1]), fmaxf(cc[1], dd[1]));
        atomicMaxF(&out[tid * 2],     v0);
        atomicMaxF(&out[tid * 2 + 1], v1);
    }
}

extern "C" void kernel_launch(void* const* d_in, const int* in_sizes, int n_in,
                              void* d_out, int out_size, void* d_ws, size_t ws_size,
                              hipStream_t stream) {
    const int*   tokens = (const int*)d_in[0];
    const int*   ends   = (const int*)d_in[1];
    const float* emb    = (const float*)d_in[2];
    const float* W      = (const float*)d_in[3];
    const float* bvec   = (const float*)d_in[4];
    float* out = (float*)d_out;
    int n = in_sizes[0];
    int C = (n + CHUNK - 1) >> LG;

    unsigned short* T_sp = (unsigned short*)d_ws;          // n*128 bf16 = 256 MB
    float*          sumE = (float*)(T_sp + (size_t)n * D); // C*128 fp32 (scanned in place)
    // total = n*256 + C*512 = 258,000,384 B for n=1e6 (same proven footprint as R6)

    init_out_kernel<<<1, 128, 0, stream>>>(out, out_size);
    fused_kernel<<<C, 256, 0, stream>>>(tokens, ends, emb, W, bvec,
                                        T_sp, sumE, out, n);
    scan_kernel<<<128, 64, 0, stream>>>(sumE, C);
    cross_kernel<<<512, 256, 0, stream>>>(ends, T_sp, sumE, bvec, out, n);
}

// Round 8
// 401.582 us; speedup vs baseline: 1.1581x; 1.1581x over previous
//
#include <hip/hip_runtime.h>
#include <hip/hip_bf16.h>

#define D      128
#define LG     9
#define CHUNK  512   // (1 << LG)

typedef __attribute__((ext_vector_type(8))) short          short8;
typedef __attribute__((ext_vector_type(8))) unsigned short ushort8;
typedef __attribute__((ext_vector_type(4))) float          floatx4;
typedef __attribute__((ext_vector_type(2))) float          floatx2;

__device__ inline float b2f(unsigned short u) {
    return __uint_as_float(((unsigned)u) << 16);
}
__device__ inline unsigned short f2bf(float f) {
    __hip_bfloat16 h = __float2bfloat16(f);
    unsigned short u;
    __builtin_memcpy(&u, &h, 2);
    return u;
}
__device__ inline short8 u2s(ushort8 u) {
    short8 s; __builtin_memcpy(&s, &u, 16); return s;
}
__device__ inline void atomicMaxF(float* addr, float v) {
    if (v >= 0.f) atomicMax((int*)addr, __float_as_int(v));
    else          atomicMin((unsigned int*)addr, __float_as_uint(v));
}

__global__ void init_out_kernel(float* out, int out_size) {
    int t = threadIdx.x;
    if (t < out_size) out[t] = -INFINITY;
}

// Pass 1: chunk-LOCAL inclusive cumsum of embedding rows (fp32 accum, bf16
// store). One wave per chunk; lane covers dims {2l, 2l+1} via float2 loads.
__global__ __launch_bounds__(128) void local_scan_kernel(
        const int* __restrict__ tokens, const float* __restrict__ emb,
        unsigned* __restrict__ T32, float* __restrict__ sumE, int n, int C) {
    __shared__ int toks[2][CHUNK];
    int tid = threadIdx.x, w = tid >> 6, lane = tid & 63;
    int cb = min(blockIdx.x * 2 + w, C - 1);   // clamp: duplicate work is benign
    int i0 = cb << LG, cnt = min(CHUNK, n - i0);
    for (int t = lane; t < cnt; t += 64) toks[w][t] = tokens[i0 + t];
    const floatx2* eb = (const floatx2*)emb;   // emb row = 64 float2
    unsigned* To = T32 + (size_t)i0 * 64 + lane;
    float rx = 0.f, ry = 0.f;
    #pragma unroll 4
    for (int j = 0; j < cnt; ++j) {
        floatx2 v = eb[(size_t)toks[w][j] * 64 + lane];
        rx += v[0]; ry += v[1];
        To[(size_t)j * 64] = ((unsigned)f2bf(rx)) | (((unsigned)f2bf(ry)) << 16);
    }
    floatx2 rr = {rx, ry};
    *(floatx2*)(sumE + (size_t)cb * D + lane * 2) = rr;
}

// Pass 2: in-place exclusive scan of chunk totals (one wave per dim).
__global__ void scan_kernel(float* sumE, int C) {
    int d    = blockIdx.x;     // 0..127
    int lane = threadIdx.x;    // 0..63
    float carry = 0.f;
    for (int c0 = 0; c0 < C; c0 += 64) {
        int c = c0 + lane;
        float v = (c < C) ? sumE[(size_t)c * D + d] : 0.f;
        float incl = v;
        #pragma unroll
        for (int off = 1; off < 64; off <<= 1) {
            float t = __shfl_up(incl, off);
            if (lane >= off) incl += t;
        }
        if (c < C) sumE[(size_t)c * D + d] = carry + incl - v;  // exclusive
        carry += __shfl(incl, 63);
    }
}

// Pass 3: h = W*(S[e]-S[i-1]) + cnt*b via MFMA; out = per-dim max.
// Wave-pair scheme (half of W^T per wave, 64 VGPR) + 2-deep software pipeline:
// tile t+1's raw rows and tile t+2's ends are in flight while tile t computes.
// Fast path feeds raw bf16 rows to dual MFMA accumulators (no converts).
__global__ __launch_bounds__(256, 3) void max_pass_kernel(
        const int* __restrict__ ends, const unsigned short* __restrict__ S,
        const float* __restrict__ prefE, const float* __restrict__ W,
        const float* __restrict__ bvec, float* __restrict__ out,
        int n, int tpp) {
    __shared__ float red[4][4][16];
    int tid = threadIdx.x, lane = tid & 63, wid = tid >> 6;
    int c  = lane & 15;   // node-in-tile / output-dim-in-tile
    int kg = lane >> 4;   // k-subgroup 0..3
    int tw = wid & 1, pair = wid >> 1;

    // This wave's half of W (bf16 fragments) + bias slice.
    short8 Wf[4][4];
    float  bc[4];
    #pragma unroll
    for (int tl = 0; tl < 4; ++tl) {
        const float* wr = W + (size_t)((tw * 4 + tl) * 16 + c) * D + kg * 8;
        bc[tl] = bvec[(tw * 4 + tl) * 16 + c];
        #pragma unroll
        for (int kk = 0; kk < 4; ++kk) {
            floatx4 f0 = *(const floatx4*)(wr + kk * 32);
            floatx4 f1 = *(const floatx4*)(wr + kk * 32 + 4);
            short8 w;
            #pragma unroll
            for (int j = 0; j < 4; ++j) { w[j] = (short)f2bf(f0[j]); w[j + 4] = (short)f2bf(f1[j]); }
            Wf[tl][kk] = w;
        }
    }
    float mx[4];
    #pragma unroll
    for (int tl = 0; tl < 4; ++tl) mx[tl] = -INFINITY;

    const ushort8* Sv = (const ushort8*)S;   // row = 16 granules of 8 bf16

#define LD_E(tt) ends[min((tt) * 16 + c, n - 1)]
#define LOAD_ROWS(tt, e, Pe, Pp) do {                                  \
        int node_ = (tt) * 16 + c;                                     \
        int pc_ = max(min(node_, n) - 1, 0);                           \
        const ushort8* pe_ = Sv + (size_t)(e) * 16 + kg;               \
        const ushort8* pp_ = Sv + (size_t)pc_ * 16 + kg;               \
        Pe[0] = pe_[0]; Pe[1] = pe_[4]; Pe[2] = pe_[8]; Pe[3] = pe_[12]; \
        Pp[0] = pp_[0]; Pp[1] = pp_[4]; Pp[2] = pp_[8]; Pp[3] = pp_[12]; \
    } while (0)

#define PROCESS(tt, e, Pe, Pp) do {                                    \
        int base_ = (tt) * 16;                                         \
        int node_ = base_ + c;                                         \
        bool vr_  = node_ < n;                                         \
        int p_  = node_ - 1;                                           \
        int pc_ = max(p_, 0);                                          \
        int ce_ = (e) >> LG, cp_ = pc_ >> LG;                          \
        bool fast_ = __all(vr_ && p_ >= 0 && ce_ == cp_);              \
        floatx4 cnt4_;                                                 \
        _Pragma("unroll")                                              \
        for (int i = 0; i < 4; ++i)                                    \
            cnt4_[i] = (float)(__shfl((e), kg * 4 + i) - (base_ + kg * 4 + i) + 1); \
        if (fast_) {                                                   \
            _Pragma("unroll")                                          \
            for (int tl = 0; tl < 4; ++tl) {                           \
                floatx4 ae_ = {0.f, 0.f, 0.f, 0.f};                    \
                floatx4 ap_ = {0.f, 0.f, 0.f, 0.f};                    \
                _Pragma("unroll")                                      \
                for (int kk = 0; kk < 4; ++kk) {                       \
                    ae_ = __builtin_amdgcn_mfma_f32_16x16x32_bf16(u2s(Pe[kk]), Wf[tl][kk], ae_, 0, 0, 0); \
                    ap_ = __builtin_amdgcn_mfma_f32_16x16x32_bf16(u2s(Pp[kk]), Wf[tl][kk], ap_, 0, 0, 0); \
                }                                                      \
                _Pragma("unroll")                                      \
                for (int i = 0; i < 4; ++i) {                          \
                    float h_ = (ae_[i] - ap_[i]) + cnt4_[i] * bc[tl];  \
                    if (base_ + kg * 4 + i < n) mx[tl] = fmaxf(mx[tl], h_); \
                }                                                      \
            }                                                          \
        } else {                                                       \
            const float* qe_ = prefE + (size_t)ce_ * D + kg * 8;       \
            const float* qp_ = prefE + (size_t)cp_ * D + kg * 8;       \
            float vm_ = vr_ ? 1.f : 0.f;                               \
            float pm_ = (p_ >= 0) ? 1.f : 0.f;                         \
            short8 A_[4];                                              \
            _Pragma("unroll")                                          \
            for (int kk = 0; kk < 4; ++kk) {                           \
                floatx4 qe0 = *(const floatx4*)(qe_ + kk * 32);        \
                floatx4 qe1 = *(const floatx4*)(qe_ + kk * 32 + 4);    \
                floatx4 qp0 = *(const floatx4*)(qp_ + kk * 32);        \
                floatx4 qp1 = *(const floatx4*)(qp_ + kk * 32 + 4);    \
                short8 a_;                                             \
                _Pragma("unroll")                                      \
                for (int j = 0; j < 4; ++j) {                          \
                    float fe0 = b2f(Pe[kk][j])     + qe0[j];           \
                    float fp0 = b2f(Pp[kk][j])     + qp0[j];           \
                    float fe1 = b2f(Pe[kk][j + 4]) + qe1[j];           \
                    float fp1 = b2f(Pp[kk][j + 4]) + qp1[j];           \
                    a_[j]     = (short)f2bf(vm_ * (fe0 - pm_ * fp0));  \
                    a_[j + 4] = (short)f2bf(vm_ * (fe1 - pm_ * fp1));  \
                }                                                      \
                A_[kk] = a_;                                           \
            }                                                          \
            _Pragma("unroll")                                          \
            for (int tl = 0; tl < 4; ++tl) {                           \
                floatx4 acc_ = {0.f, 0.f, 0.f, 0.f};                   \
                _Pragma("unroll")                                      \
                for (int kk = 0; kk < 4; ++kk)                         \
                    acc_ = __builtin_amdgcn_mfma_f32_16x16x32_bf16(A_[kk], Wf[tl][kk], acc_, 0, 0, 0); \
                _Pragma("unroll")                                      \
                for (int i = 0; i < 4; ++i) {                          \
                    float h_ = acc_[i] + cnt4_[i] * bc[tl];            \
                    if (base_ + kg * 4 + i < n) mx[tl] = fmaxf(mx[tl], h_); \
                }                                                      \
            }                                                          \
        }                                                              \
    } while (0)

    int t0 = (blockIdx.x * 2 + pair) * tpp;
    ushort8 Ae[4], Ap[4], Be[4], Bp[4];
    int e0 = LD_E(t0);
    LOAD_ROWS(t0, e0, Ae, Ap);
    int e1 = LD_E(t0 + 1);
    for (int tt = t0; tt < t0 + tpp; tt += 2) {
        LOAD_ROWS(tt + 1, e1, Be, Bp);
        int e2 = LD_E(tt + 2);
        PROCESS(tt, e0, Ae, Ap);
        LOAD_ROWS(tt + 2, e2, Ae, Ap);
        int e3 = LD_E(tt + 3);
        PROCESS(tt + 1, e1, Be, Bp);
        e0 = e2; e1 = e3;
    }

    // Reduce across the 4 k-subgroups (same output dim (tw*4+tl)*16+c).
    #pragma unroll
    for (int tl = 0; tl < 4; ++tl) {
        float v = mx[tl];
        v = fmaxf(v, __shfl_xor(v, 16));
        v = fmaxf(v, __shfl_xor(v, 32));
        mx[tl] = v;
    }
    if (kg == 0) {
        #pragma unroll
        for (int tl = 0; tl < 4; ++tl) red[wid][tl][c] = mx[tl];
    }
    __syncthreads();
    if (tid < 128) {
        int twf = tid >> 6;          // waves {twf, twf+2} share tw = twf
        int tl  = (tid >> 4) & 3;
        int cc  = tid & 15;
        float v = fmaxf(red[twf][tl][cc], red[twf + 2][tl][cc]);
        atomicMaxF(&out[(twf * 4 + tl) * 16 + cc], v);
    }
}

extern "C" void kernel_launch(void* const* d_in, const int* in_sizes, int n_in,
                              void* d_out, int out_size, void* d_ws, size_t ws_size,
                              hipStream_t stream) {
    const int*   tokens = (const int*)d_in[0];
    const int*   ends   = (const int*)d_in[1];
    const float* emb    = (const float*)d_in[2];
    const float* W      = (const float*)d_in[3];
    const float* bvec   = (const float*)d_in[4];
    float* out = (float*)d_out;
    int n = in_sizes[0];
    int C = (n + CHUNK - 1) >> LG;

    unsigned short* S    = (unsigned short*)d_ws;          // n*128 bf16 = 256 MB
    float*          sumE = (float*)(S + (size_t)n * D);    // C*128 fp32 (scanned in place)
    // total = n*256 + C*512 = 257,000,448 B for n=1e6 (same proven footprint as R5)

    init_out_kernel<<<1, 128, 0, stream>>>(out, out_size);
    local_scan_kernel<<<(C + 1) / 2, 128, 0, stream>>>(tokens, emb,
                                                       (unsigned*)S, sumE, n, C);
    scan_kernel<<<128, 64, 0, stream>>>(sumE, C);

    int n_tiles = (n + 15) / 16;
    int nblocks = 768;                       // 3 blocks/CU; 1536 pair-streams
    int pairs   = nblocks * 2;
    int tpp = ((n_tiles + pairs - 1) / pairs + 1) & ~1;   // even, padded (masked)
    max_pass_kernel<<<nblocks, 256, 0, stream>>>(ends, S, sumE, W, bvec, out,
                                                 n, tpp);
}

// Round 9
// 277.989 us; speedup vs baseline: 1.6730x; 1.4446x over previous
//
#include <hip/hip_runtime.h>
#include <hip/hip_bf16.h>

#define D      128
#define LG     9
#define CHUNK  512   // (1 << LG)

typedef __attribute__((ext_vector_type(8))) short          short8;
typedef __attribute__((ext_vector_type(8))) unsigned short ushort8;
typedef __attribute__((ext_vector_type(4))) float          floatx4;
typedef __attribute__((ext_vector_type(2))) float          floatx2;

__device__ inline float b2f(unsigned short u) {
    return __uint_as_float(((unsigned)u) << 16);
}
__device__ inline unsigned short f2bf(float f) {
    __hip_bfloat16 h = __float2bfloat16(f);
    unsigned short u;
    __builtin_memcpy(&u, &h, 2);
    return u;
}
__device__ inline short8 u2s(ushort8 u) {
    short8 s; __builtin_memcpy(&s, &u, 16); return s;
}
__device__ inline void atomicMaxF(float* addr, float v) {
    if (v >= 0.f) atomicMax((int*)addr, __float_as_int(v));
    else          atomicMin((unsigned int*)addr, __float_as_uint(v));
}

__global__ void init_out_kernel(float* out, int out_size) {
    int t = threadIdx.x;
    if (t < out_size) out[t] = -INFINITY;
}

// Pass 1: per-chunk embedding sums (no row stores). One wave per chunk.
__global__ __launch_bounds__(256) void chunk_sums_kernel(
        const int* __restrict__ tokens, const float* __restrict__ emb,
        float* __restrict__ sumE, int n, int C) {
    __shared__ int toks[4][CHUNK];
    int tid = threadIdx.x, w = tid >> 6, lane = tid & 63;
    int cb = min(blockIdx.x * 4 + w, C - 1);   // tail duplicate: same bytes, benign
    int i0 = cb << LG, cnt = min(CHUNK, n - i0);
    for (int t = lane; t < cnt; t += 64) toks[w][t] = tokens[i0 + t];
    __syncthreads();
    const floatx2* eb = (const floatx2*)emb;   // emb row = 64 float2
    float rx = 0.f, ry = 0.f;
    #pragma unroll 4
    for (int j = 0; j < cnt; ++j) {
        floatx2 v = eb[(size_t)toks[w][j] * 64 + lane];
        rx += v[0]; ry += v[1];
    }
    floatx2 rr = {rx, ry};
    *(floatx2*)(sumE + (size_t)cb * D + lane * 2) = rr;
}

// Pass 2: in-place exclusive scan of chunk totals (one wave per dim).
__global__ void scan_kernel(float* sumE, int C) {
    int d    = blockIdx.x;     // 0..127
    int lane = threadIdx.x;    // 0..63
    float carry = 0.f;
    for (int c0 = 0; c0 < C; c0 += 64) {
        int c = c0 + lane;
        float v = (c < C) ? sumE[(size_t)c * D + d] : 0.f;
        float incl = v;
        #pragma unroll
        for (int off = 1; off < 64; off <<= 1) {
            float t = __shfl_up(incl, off);
            if (lane >= off) incl += t;
        }
        if (c < C) sumE[(size_t)c * D + d] = carry + incl - v;  // exclusive
        carry += __shfl(incl, 63);
    }
}

// Pass 3: re-gather, GLOBAL inclusive cumsum (fp32 carry-in from pref), store
// bf16 rows. One wave per chunk, lane owns dims {2l, 2l+1}.
__global__ __launch_bounds__(128) void write_S_kernel(
        const int* __restrict__ tokens, const float* __restrict__ emb,
        const float* __restrict__ pref, unsigned* __restrict__ T32,
        int n, int C) {
    __shared__ int toks[2][CHUNK];
    int tid = threadIdx.x, w = tid >> 6, lane = tid & 63;
    int cb = min(blockIdx.x * 2 + w, C - 1);   // tail duplicate: same bytes, benign
    int i0 = cb << LG, cnt = min(CHUNK, n - i0);
    for (int t = lane; t < cnt; t += 64) toks[w][t] = tokens[i0 + t];
    __syncthreads();
    const floatx2* eb = (const floatx2*)emb;
    floatx2 r0 = *(const floatx2*)(pref + (size_t)cb * D + lane * 2);
    float rx = r0[0], ry = r0[1];
    unsigned* To = T32 + (size_t)i0 * 64 + lane;
    #pragma unroll 4
    for (int j = 0; j < cnt; ++j) {
        floatx2 v = eb[(size_t)toks[w][j] * 64 + lane];
        rx += v[0]; ry += v[1];
        To[(size_t)j * 64] = ((unsigned)f2bf(rx)) | (((unsigned)f2bf(ry)) << 16);
    }
}

// Pass 4: h = (W*S[e]) - (W*S[i-1]) + cnt*b via dual-MFMA; out = per-dim max.
// Branch-free (global cumsum: no prefE, no slow path). Full W^T per wave
// (64 VGPR), 2-deep software pipeline, INTERLEAVED tile assignment: wave g
// takes tiles g, g+STRIDE, ... so all waves read one dense sliding window.
__global__ __launch_bounds__(256, 2) void max_pass_kernel(
        const int* __restrict__ ends, const unsigned short* __restrict__ S,
        const float* __restrict__ W, const float* __restrict__ bvec,
        float* __restrict__ out, int n, int tpw) {
    __shared__ float red[4][8][16];
    int tid = threadIdx.x, lane = tid & 63, wid = tid >> 6;
    int c  = lane & 15;   // node-in-tile / output-dim-in-tile
    int kg = lane >> 4;   // k-subgroup 0..3

    // Full W^T as bf16 fragments + bias.
    short8 Wf[8][4];
    float  bc[8];
    #pragma unroll
    for (int tl = 0; tl < 8; ++tl) {
        const float* wr = W + (size_t)(tl * 16 + c) * D + kg * 8;
        bc[tl] = bvec[tl * 16 + c];
        #pragma unroll
        for (int kk = 0; kk < 4; ++kk) {
            floatx4 f0 = *(const floatx4*)(wr + kk * 32);
            floatx4 f1 = *(const floatx4*)(wr + kk * 32 + 4);
            short8 w;
            #pragma unroll
            for (int j = 0; j < 4; ++j) { w[j] = (short)f2bf(f0[j]); w[j + 4] = (short)f2bf(f1[j]); }
            Wf[tl][kk] = w;
        }
    }
    float mx[8];
    #pragma unroll
    for (int tl = 0; tl < 8; ++tl) mx[tl] = -INFINITY;

    const ushort8* Sv = (const ushort8*)S;   // row = 16 granules of 8 bf16
    int gw = blockIdx.x * 4 + wid;
    int STRIDE = gridDim.x * 4;
    ushort8 zero8 = {0, 0, 0, 0, 0, 0, 0, 0};

#define TIDX(k)  (gw + (k) * STRIDE)
#define LD_E(k)  ends[min(TIDX(k) * 16 + c, n - 1)]
#define LOAD_ROWS(k, e, Pe, Pp) do {                                     \
        int node_ = TIDX(k) * 16 + c;                                    \
        int pc_ = max(min(node_, n) - 1, 0);                             \
        const ushort8* pe_ = Sv + (size_t)(e) * 16 + kg;                 \
        const ushort8* pp_ = Sv + (size_t)pc_ * 16 + kg;                 \
        Pe[0] = pe_[0]; Pe[1] = pe_[4]; Pe[2] = pe_[8]; Pe[3] = pe_[12]; \
        Pp[0] = pp_[0]; Pp[1] = pp_[4]; Pp[2] = pp_[8]; Pp[3] = pp_[12]; \
        if (node_ == 0) { Pp[0] = zero8; Pp[1] = zero8; Pp[2] = zero8; Pp[3] = zero8; } \
    } while (0)

#define PROCESS(k, e, Pe, Pp) do {                                       \
        int base_ = TIDX(k) * 16;                                        \
        floatx4 cnt4_;                                                   \
        _Pragma("unroll")                                                \
        for (int i = 0; i < 4; ++i)                                      \
            cnt4_[i] = (float)(__shfl((e), kg * 4 + i) - (base_ + kg * 4 + i) + 1); \
        _Pragma("unroll")                                                \
        for (int tl = 0; tl < 8; ++tl) {                                 \
            floatx4 ae_ = {0.f, 0.f, 0.f, 0.f};                          \
            floatx4 ap_ = {0.f, 0.f, 0.f, 0.f};                          \
            _Pragma("unroll")                                            \
            for (int kk = 0; kk < 4; ++kk) {                             \
                ae_ = __builtin_amdgcn_mfma_f32_16x16x32_bf16(u2s(Pe[kk]), Wf[tl][kk], ae_, 0, 0, 0); \
                ap_ = __builtin_amdgcn_mfma_f32_16x16x32_bf16(u2s(Pp[kk]), Wf[tl][kk], ap_, 0, 0, 0); \
            }                                                            \
            _Pragma("unroll")                                            \
            for (int i = 0; i < 4; ++i) {                                \
                float h_ = (ae_[i] - ap_[i]) + cnt4_[i] * bc[tl];        \
                if (base_ + kg * 4 + i < n) mx[tl] = fmaxf(mx[tl], h_);  \
            }                                                            \
        }                                                                \
    } while (0)

    ushort8 Ae[4], Ap[4], Be[4], Bp[4];
    int e0 = LD_E(0);
    LOAD_ROWS(0, e0, Ae, Ap);
    int e1 = LD_E(1);
    for (int k = 0; k < tpw; k += 2) {
        LOAD_ROWS(k + 1, e1, Be, Bp);
        int e2 = LD_E(k + 2);
        PROCESS(k, e0, Ae, Ap);
        LOAD_ROWS(k + 2, e2, Ae, Ap);
        int e3 = LD_E(k + 3);
        PROCESS(k + 1, e1, Be, Bp);
        e0 = e2; e1 = e3;
    }

    // Reduce across the 4 k-subgroups (same output dim tl*16+c).
    #pragma unroll
    for (int tl = 0; tl < 8; ++tl) {
        float v = mx[tl];
        v = fmaxf(v, __shfl_xor(v, 16));
        v = fmaxf(v, __shfl_xor(v, 32));
        mx[tl] = v;
    }
    if (kg == 0) {
        #pragma unroll
        for (int tl = 0; tl < 8; ++tl) red[wid][tl][c] = mx[tl];
    }
    __syncthreads();
    if (tid < 128) {
        int tl = tid >> 4, cc = tid & 15;
        float v = fmaxf(fmaxf(red[0][tl][cc], red[1][tl][cc]),
                        fmaxf(red[2][tl][cc], red[3][tl][cc]));
        atomicMaxF(&out[tl * 16 + cc], v);
    }
}

extern "C" void kernel_launch(void* const* d_in, const int* in_sizes, int n_in,
                              void* d_out, int out_size, void* d_ws, size_t ws_size,
                              hipStream_t stream) {
    const int*   tokens = (const int*)d_in[0];
    const int*   ends   = (const int*)d_in[1];
    const float* emb    = (const float*)d_in[2];
    const float* W      = (const float*)d_in[3];
    const float* bvec   = (const float*)d_in[4];
    float* out = (float*)d_out;
    int n = in_sizes[0];
    int C = (n + CHUNK - 1) >> LG;

    unsigned short* S    = (unsigned short*)d_ws;          // n*128 bf16 = 256 MB
    float*          sumE = (float*)(S + (size_t)n * D);    // C*128 fp32 (scanned in place)
    // total = n*256 + C*512 = 257,000,448 B for n=1e6 (same proven footprint)

    init_out_kernel<<<1, 128, 0, stream>>>(out, out_size);
    chunk_sums_kernel<<<(C + 3) / 4, 256, 0, stream>>>(tokens, emb, sumE, n, C);
    scan_kernel<<<128, 64, 0, stream>>>(sumE, C);
    write_S_kernel<<<(C + 1) / 2, 128, 0, stream>>>(tokens, emb, sumE,
                                                    (unsigned*)S, n, C);

    int n_tiles = (n + 15) / 16;
    int nblocks = 512;                        // 2 blocks/CU, 2048 wave-streams
    int waves   = nblocks * 4;
    int tpw = ((n_tiles + waves - 1) / waves + 1) & ~1;   // even, tail masked
    max_pass_kernel<<<nblocks, 256, 0, stream>>>(ends, S, W, bvec, out, n, tpw);
}

// Round 10
// 272.191 us; speedup vs baseline: 1.7086x; 1.0213x over previous
//
#include <hip/hip_runtime.h>
#include <hip/hip_bf16.h>

#define D      128
#define LG     9
#define CHUNK  512   // (1 << LG)

typedef __attribute__((ext_vector_type(8))) short          short8;
typedef __attribute__((ext_vector_type(8))) unsigned short ushort8;
typedef __attribute__((ext_vector_type(4))) float          floatx4;
typedef __attribute__((ext_vector_type(2))) float          floatx2;

__device__ inline float b2f(unsigned short u) {
    return __uint_as_float(((unsigned)u) << 16);
}
__device__ inline unsigned short f2bf(float f) {
    __hip_bfloat16 h = __float2bfloat16(f);
    unsigned short u;
    __builtin_memcpy(&u, &h, 2);
    return u;
}
__device__ inline short8 u2s(ushort8 u) {
    short8 s; __builtin_memcpy(&s, &u, 16); return s;
}
__device__ inline void atomicMaxF(float* addr, float v) {
    if (v >= 0.f) atomicMax((int*)addr, __float_as_int(v));
    else          atomicMin((unsigned int*)addr, __float_as_uint(v));
}

__global__ void init_out_kernel(float* out, int out_size) {
    int t = threadIdx.x;
    if (t < out_size) out[t] = -INFINITY;
}

// Pass 1: per-chunk embedding sums (no row stores). One wave per chunk.
__global__ __launch_bounds__(256) void chunk_sums_kernel(
        const int* __restrict__ tokens, const float* __restrict__ emb,
        float* __restrict__ sumE, int n, int C) {
    __shared__ int toks[4][CHUNK];
    int tid = threadIdx.x, w = tid >> 6, lane = tid & 63;
    int cb = min(blockIdx.x * 4 + w, C - 1);   // tail duplicate: same bytes, benign
    int i0 = cb << LG, cnt = min(CHUNK, n - i0);
    for (int t = lane; t < cnt; t += 64) toks[w][t] = tokens[i0 + t];
    __syncthreads();
    const floatx2* eb = (const floatx2*)emb;   // emb row = 64 float2
    float rx = 0.f, ry = 0.f;
    #pragma unroll 4
    for (int j = 0; j < cnt; ++j) {
        floatx2 v = eb[(size_t)toks[w][j] * 64 + lane];
        rx += v[0]; ry += v[1];
    }
    floatx2 rr = {rx, ry};
    *(floatx2*)(sumE + (size_t)cb * D + lane * 2) = rr;
}

// Pass 2: in-place exclusive scan of chunk totals (one wave per dim).
__global__ void scan_kernel(float* sumE, int C) {
    int d    = blockIdx.x;     // 0..127
    int lane = threadIdx.x;    // 0..63
    float carry = 0.f;
    for (int c0 = 0; c0 < C; c0 += 64) {
        int c = c0 + lane;
        float v = (c < C) ? sumE[(size_t)c * D + d] : 0.f;
        float incl = v;
        #pragma unroll
        for (int off = 1; off < 64; off <<= 1) {
            float t = __shfl_up(incl, off);
            if (lane >= off) incl += t;
        }
        if (c < C) sumE[(size_t)c * D + d] = carry + incl - v;  // exclusive
        carry += __shfl(incl, 63);
    }
}

// Pass 3: re-gather, GLOBAL inclusive cumsum (fp32 carry-in from pref), store
// bf16 rows with NONTEMPORAL stores (don't evict emb from L3 — the S stream
// is written once and consumed from HBM by max_pass anyway).
__global__ __launch_bounds__(128) void write_S_kernel(
        const int* __restrict__ tokens, const float* __restrict__ emb,
        const float* __restrict__ pref, unsigned* __restrict__ T32,
        int n, int C) {
    __shared__ int toks[2][CHUNK];
    int tid = threadIdx.x, w = tid >> 6, lane = tid & 63;
    int cb = min(blockIdx.x * 2 + w, C - 1);   // tail duplicate: same bytes, benign
    int i0 = cb << LG, cnt = min(CHUNK, n - i0);
    for (int t = lane; t < cnt; t += 64) toks[w][t] = tokens[i0 + t];
    __syncthreads();
    const floatx2* eb = (const floatx2*)emb;
    floatx2 r0 = *(const floatx2*)(pref + (size_t)cb * D + lane * 2);
    float rx = r0[0], ry = r0[1];
    unsigned* To = T32 + (size_t)i0 * 64 + lane;
    #pragma unroll 4
    for (int j = 0; j < cnt; ++j) {
        floatx2 v = eb[(size_t)toks[w][j] * 64 + lane];
        rx += v[0]; ry += v[1];
        unsigned pk = ((unsigned)f2bf(rx)) | (((unsigned)f2bf(ry)) << 16);
        __builtin_nontemporal_store(pk, To + (size_t)j * 64);
    }
}

// Pass 4: h = (W*S[e]) - (W*S[i-1]) + cnt*b via dual-MFMA; out = per-dim max.
// Branch-free (global cumsum: no prefE, no slow path). Full W^T per wave
// (64 VGPR), 2-deep software pipeline, INTERLEAVED tile assignment: wave g
// takes tiles g, g+STRIDE, ... so all waves read one dense sliding window.
__global__ __launch_bounds__(256, 2) void max_pass_kernel(
        const int* __restrict__ ends, const unsigned short* __restrict__ S,
        const float* __restrict__ W, const float* __restrict__ bvec,
        float* __restrict__ out, int n, int tpw) {
    __shared__ float red[4][8][16];
    int tid = threadIdx.x, lane = tid & 63, wid = tid >> 6;
    int c  = lane & 15;   // node-in-tile / output-dim-in-tile
    int kg = lane >> 4;   // k-subgroup 0..3

    // Full W^T as bf16 fragments + bias.
    short8 Wf[8][4];
    float  bc[8];
    #pragma unroll
    for (int tl = 0; tl < 8; ++tl) {
        const float* wr = W + (size_t)(tl * 16 + c) * D + kg * 8;
        bc[tl] = bvec[tl * 16 + c];
        #pragma unroll
        for (int kk = 0; kk < 4; ++kk) {
            floatx4 f0 = *(const floatx4*)(wr + kk * 32);
            floatx4 f1 = *(const floatx4*)(wr + kk * 32 + 4);
            short8 w;
            #pragma unroll
            for (int j = 0; j < 4; ++j) { w[j] = (short)f2bf(f0[j]); w[j + 4] = (short)f2bf(f1[j]); }
            Wf[tl][kk] = w;
        }
    }
    float mx[8];
    #pragma unroll
    for (int tl = 0; tl < 8; ++tl) mx[tl] = -INFINITY;

    const ushort8* Sv = (const ushort8*)S;   // row = 16 granules of 8 bf16
    int gw = blockIdx.x * 4 + wid;
    int STRIDE = gridDim.x * 4;
    ushort8 zero8 = {0, 0, 0, 0, 0, 0, 0, 0};

#define TIDX(k)  (gw + (k) * STRIDE)
#define LD_E(k)  ends[min(TIDX(k) * 16 + c, n - 1)]
#define LOAD_ROWS(k, e, Pe, Pp) do {                                     \
        int node_ = TIDX(k) * 16 + c;                                    \
        int pc_ = max(min(node_, n) - 1, 0);                             \
        const ushort8* pe_ = Sv + (size_t)(e) * 16 + kg;                 \
        const ushort8* pp_ = Sv + (size_t)pc_ * 16 + kg;                 \
        Pe[0] = pe_[0]; Pe[1] = pe_[4]; Pe[2] = pe_[8]; Pe[3] = pe_[12]; \
        Pp[0] = pp_[0]; Pp[1] = pp_[4]; Pp[2] = pp_[8]; Pp[3] = pp_[12]; \
        if (node_ == 0) { Pp[0] = zero8; Pp[1] = zero8; Pp[2] = zero8; Pp[3] = zero8; } \
    } while (0)

#define PROCESS(k, e, Pe, Pp) do {                                       \
        int base_ = TIDX(k) * 16;                                        \
        floatx4 cnt4_;                                                   \
        _Pragma("unroll")                                                \
        for (int i = 0; i < 4; ++i)                                      \
            cnt4_[i] = (float)(__shfl((e), kg * 4 + i) - (base_ + kg * 4 + i) + 1); \
        _Pragma("unroll")                                                \
        for (int tl = 0; tl < 8; ++tl) {                                 \
            floatx4 ae_ = {0.f, 0.f, 0.f, 0.f};                          \
            floatx4 ap_ = {0.f, 0.f, 0.f, 0.f};                          \
            _Pragma("unroll")                                            \
            for (int kk = 0; kk < 4; ++kk) {                             \
                ae_ = __builtin_amdgcn_mfma_f32_16x16x32_bf16(u2s(Pe[kk]), Wf[tl][kk], ae_, 0, 0, 0); \
                ap_ = __builtin_amdgcn_mfma_f32_16x16x32_bf16(u2s(Pp[kk]), Wf[tl][kk], ap_, 0, 0, 0); \
            }                                                            \
            _Pragma("unroll")                                            \
            for (int i = 0; i < 4; ++i) {                                \
                float h_ = (ae_[i] - ap_[i]) + cnt4_[i] * bc[tl];        \
                if (base_ + kg * 4 + i < n) mx[tl] = fmaxf(mx[tl], h_);  \
            }                                                            \
        }                                                                \
    } while (0)

    ushort8 Ae[4], Ap[4], Be[4], Bp[4];
    int e0 = LD_E(0);
    LOAD_ROWS(0, e0, Ae, Ap);
    int e1 = LD_E(1);
    for (int k = 0; k < tpw; k += 2) {
        LOAD_ROWS(k + 1, e1, Be, Bp);
        int e2 = LD_E(k + 2);
        PROCESS(k, e0, Ae, Ap);
        LOAD_ROWS(k + 2, e2, Ae, Ap);
        int e3 = LD_E(k + 3);
        PROCESS(k + 1, e1, Be, Bp);
        e0 = e2; e1 = e3;
    }

    // Reduce across the 4 k-subgroups (same output dim tl*16+c).
    #pragma unroll
    for (int tl = 0; tl < 8; ++tl) {
        float v = mx[tl];
        v = fmaxf(v, __shfl_xor(v, 16));
        v = fmaxf(v, __shfl_xor(v, 32));
        mx[tl] = v;
    }
    if (kg == 0) {
        #pragma unroll
        for (int tl = 0; tl < 8; ++tl) red[wid][tl][c] = mx[tl];
    }
    __syncthreads();
    if (tid < 128) {
        int tl = tid >> 4, cc = tid & 15;
        float v = fmaxf(fmaxf(red[0][tl][cc], red[1][tl][cc]),
                        fmaxf(red[2][tl][cc], red[3][tl][cc]));
        atomicMaxF(&out[tl * 16 + cc], v);
    }
}

extern "C" void kernel_launch(void* const* d_in, const int* in_sizes, int n_in,
                              void* d_out, int out_size, void* d_ws, size_t ws_size,
                              hipStream_t stream) {
    const int*   tokens = (const int*)d_in[0];
    const int*   ends   = (const int*)d_in[1];
    const float* emb    = (const float*)d_in[2];
    const float* W      = (const float*)d_in[3];
    const float* bvec   = (const float*)d_in[4];
    float* out = (float*)d_out;
    int n = in_sizes[0];
    int C = (n + CHUNK - 1) >> LG;

    unsigned short* S    = (unsigned short*)d_ws;          // n*128 bf16 = 256 MB
    float*          sumE = (float*)(S + (size_t)n * D);    // C*128 fp32 (scanned in place)
    // total = n*256 + C*512 = 257,000,448 B for n=1e6 (same proven footprint)

    init_out_kernel<<<1, 128, 0, stream>>>(out, out_size);
    chunk_sums_kernel<<<(C + 3) / 4, 256, 0, stream>>>(tokens, emb, sumE, n, C);
    scan_kernel<<<128, 64, 0, stream>>>(sumE, C);
    write_S_kernel<<<(C + 1) / 2, 128, 0, stream>>>(tokens, emb, sumE,
                                                    (unsigned*)S, n, C);

    int n_tiles = (n + 15) / 16;
    int nblocks = 512;                        // 2 blocks/CU, 2048 wave-streams
    int waves   = nblocks * 4;
    int tpw = ((n_tiles + waves - 1) / waves + 1) & ~1;   // even, tail masked
    max_pass_kernel<<<nblocks, 256, 0, stream>>>(ends, S, W, bvec, out, n, tpw);
}